// Round 15
// baseline (521.804 us; speedup 1.0000x reference)
//
#include <hip/hip_runtime.h>
#include <hip/hip_bf16.h>

#define B_    8
#define S_    2048
#define HID_  512
#define H_    8
#define D_    64
#define FF_   2048
#define QN_   1664   // padded qkvb width: q 512 | k 512 | v 512 | beta 8 (pad 128)
#define NCH_  32     // S/64 chunks
#define SLOWSTRIDE (1544 * 512)   // fw_slow_w per-layer stride (floats)

typedef unsigned short u16;
typedef __attribute__((ext_vector_type(8))) short short8;
typedef __attribute__((ext_vector_type(4))) float f32x4;

__device__ __forceinline__ u16 f2bf(float x) {           // RNE fp32->bf16
  unsigned u = __builtin_bit_cast(unsigned, x);
  unsigned r = (u + 0x7FFFu + ((u >> 16) & 1u)) >> 16;
  return (u16)r;
}
__device__ __forceinline__ float bf2f(u16 v) {
  return __builtin_bit_cast(float, (unsigned)v << 16);
}
__device__ __forceinline__ void gload16(const void* g, void* l) {
  __builtin_amdgcn_global_load_lds(
      (const __attribute__((address_space(1))) unsigned int*)g,
      (__attribute__((address_space(3))) unsigned int*)l, 16, 0, 0);
}

// 64x64x64 product C[r][c] = sum_k F[r][k]*G[c][k], bf16 LDS operands.
template<int FS, int GS>
__device__ __forceinline__ void prod64(const u16* __restrict__ F,
                                       const u16* __restrict__ G,
                                       int wrow0, int lane, f32x4 acc[4])
{
  short8 f0 = *(const short8*)&F[(wrow0 + (lane & 15)) * FS + ((lane >> 4) * 8)];
  short8 f1 = *(const short8*)&F[(wrow0 + (lane & 15)) * FS + 32 + ((lane >> 4) * 8)];
  #pragma unroll
  for (int c0 = 0; c0 < 4; ++c0) {
    short8 g0 = *(const short8*)&G[(c0 * 16 + (lane & 15)) * GS + ((lane >> 4) * 8)];
    short8 g1 = *(const short8*)&G[(c0 * 16 + (lane & 15)) * GS + 32 + ((lane >> 4) * 8)];
    acc[c0] = __builtin_amdgcn_mfma_f32_16x16x32_bf16(f0, g0, acc[c0], 0, 0, 0);
    acc[c0] = __builtin_amdgcn_mfma_f32_16x16x32_bf16(f1, g1, acc[c0], 0, 0, 0);
  }
}

// ---------------------------------------------------------------------------
// bf16 GEMM: BK=32 double-buffered gload_lds staging, both-sides swizzle,
// 4-pass LDS-staged epilogue, XCD-aware block swizzle (1D grid, %8==0).
// ---------------------------------------------------------------------------
template<bool BIAS, bool RELU, bool RES, bool OUTBF, bool TRANS, bool QKVB>
__global__ __launch_bounds__(256, 4) void gemm_bf(
    const u16* __restrict__ A, const u16* __restrict__ W,
    const float* __restrict__ bias, const float* __restrict__ res,
    void* __restrict__ Cout, int M, int N, int K, int nx)
{
  __shared__ __align__(16) u16 SH[16384];   // 32KB: [As0|Bs0|As1|Bs1]
  const int tid = threadIdx.x, lane = tid & 63, wv = tid >> 6;
  const int nwg = gridDim.x;
  const int l = ((blockIdx.x & 7) * (nwg >> 3)) + (blockIdx.x >> 3);
  const int bm = (l / nx) * 128, bn = (l % nx) * 128;
  const int wr = wv >> 1, wc = wv & 1;
  const int row16 = lane & 15, kg = lane >> 4;
  const int srow = lane >> 2;
  const int ssoff = ((lane & 3) ^ (srow & 3)) * 16;

  f32x4 acc[4][4] = {};
  const int ktiles = K >> 5;

  auto STAGE = [&](int buf, int kt) {
    u16* As = &SH[buf * 8192];
    u16* Bs = &SH[buf * 8192 + 4096];
    #pragma unroll
    for (int i = 0; i < 2; ++i) {
      const int r = i * 64 + wv * 16;
      const char* ga = (const char*)(A + (size_t)(bm + r + srow) * K + (size_t)kt * 32) + ssoff;
      gload16(ga, &As[r * 32]);
      const char* gw = (const char*)(W + (size_t)(bn + r + srow) * K + (size_t)kt * 32) + ssoff;
      gload16(gw, &Bs[r * 32]);
    }
  };

  STAGE(0, 0);
  __syncthreads();
  int buf = 0;
  for (int kt = 0; kt < ktiles; ++kt) {
    if (kt + 1 < ktiles) STAGE(buf ^ 1, kt + 1);
    const u16* As = &SH[buf * 8192];
    const u16* Bs = &SH[buf * 8192 + 4096];
    short8 af[4], bf_[4];
    #pragma unroll
    for (int m = 0; m < 4; ++m) {
      const int lrow = wr * 64 + m * 16 + row16;
      af[m] = *(const short8*)&As[lrow * 32 + (kg ^ (lrow & 3)) * 8];
    }
    #pragma unroll
    for (int n = 0; n < 4; ++n) {
      const int lrow = wc * 64 + n * 16 + row16;
      bf_[n] = *(const short8*)&Bs[lrow * 32 + (kg ^ (lrow & 3)) * 8];
    }
    #pragma unroll
    for (int m = 0; m < 4; ++m)
      #pragma unroll
      for (int n = 0; n < 4; ++n)
        acc[m][n] = __builtin_amdgcn_mfma_f32_16x16x32_bf16(af[m], bf_[n], acc[m][n], 0, 0, 0);
    __syncthreads();
    buf ^= 1;
  }

  if (QKVB) {
    const int span0 = bn + wc * 64;
    #pragma unroll
    for (int m = 0; m < 4; ++m) {
      #pragma unroll
      for (int j = 0; j < 4; ++j) {
        if (span0 < 1024) {
          float v0 = acc[m][0][j], v1 = acc[m][1][j];
          float v2 = acc[m][2][j], v3 = acc[m][3][j];
          float mx = fmaxf(fmaxf(v0, v1), fmaxf(v2, v3));
          #pragma unroll
          for (int off = 1; off < 16; off <<= 1) mx = fmaxf(mx, __shfl_xor(mx, off));
          float e0 = __expf(v0 - mx), e1 = __expf(v1 - mx);
          float e2 = __expf(v2 - mx), e3 = __expf(v3 - mx);
          float s = (e0 + e1) + (e2 + e3);
          #pragma unroll
          for (int off = 1; off < 16; off <<= 1) s += __shfl_xor(s, off);
          float r = 1.f / s;
          acc[m][0][j] = e0 * r; acc[m][1][j] = e1 * r;
          acc[m][2][j] = e2 * r; acc[m][3][j] = e3 * r;
        } else if (span0 >= 1536) {
          #pragma unroll
          for (int n = 0; n < 4; ++n)
            acc[m][n][j] = 1.f / (1.f + __expf(-acc[m][n][j]));
        }
      }
    }
  }

  float* LD = (float*)SH;
  #pragma unroll
  for (int p = 0; p < 4; ++p) {
    if (p) __syncthreads();
    if (wr == (p >> 1)) {
      #pragma unroll
      for (int mm = 0; mm < 2; ++mm) {
        const int m = (p & 1) * 2 + mm;
        #pragma unroll
        for (int n = 0; n < 4; ++n)
          #pragma unroll
          for (int j = 0; j < 4; ++j)
            LD[(mm * 16 + kg * 4 + j) * 132 + wc * 64 + n * 16 + row16] = acc[m][n][j];
      }
    }
    __syncthreads();
    #pragma unroll
    for (int step = 0; step < 4; ++step) {
      int linear = step * 256 + tid;
      int row = linear >> 5, q = linear & 31;
      float4 v = *(const float4*)&LD[row * 132 + q * 4];
      const int grow = bm + p * 32 + row;
      const int gcol = bn + q * 4;
      if (BIAS) {
        float4 b4 = *(const float4*)&bias[gcol];
        v.x += b4.x; v.y += b4.y; v.z += b4.z; v.w += b4.w;
      }
      if (RES) {
        float4 r4 = *(const float4*)&res[(size_t)grow * N + gcol];
        v.x += r4.x; v.y += r4.y; v.z += r4.z; v.w += r4.w;
      }
      if (RELU) {
        v.x = fmaxf(v.x, 0.f); v.y = fmaxf(v.y, 0.f);
        v.z = fmaxf(v.z, 0.f); v.w = fmaxf(v.w, 0.f);
      }
      size_t gr = TRANS ? ((size_t)(grow & 7) * S_ + (grow >> 3)) : (size_t)grow;
      if (OUTBF) {
        uint2 pk;
        pk.x = (unsigned)f2bf(v.x) | ((unsigned)f2bf(v.y) << 16);
        pk.y = (unsigned)f2bf(v.z) | ((unsigned)f2bf(v.w) << 16);
        *(uint2*)&((u16*)Cout)[gr * N + gcol] = pk;
      } else {
        *(float4*)&((float*)Cout)[gr * N + gcol] = v;
      }
    }
  }
}

// ---------------------------------------------------------------------------
__global__ __launch_bounds__(256) void conv_w(const float* __restrict__ s,
                                              u16* __restrict__ d, int n, int npad)
{
  int i = blockIdx.x * 256 + threadIdx.x;
  if (i < npad) d[i] = (i < n) ? f2bf(s[i]) : (u16)0;
}

// slow_w reordered head-aligned: rows [q 512 | k 512 | v 512 | beta 8 | pad]
__global__ __launch_bounds__(256) void conv_slow(const float* __restrict__ s,
                                                 u16* __restrict__ d)
{
  int r = blockIdx.x;
  int src;
  if (r < 512)       src = (r >> 6) * 193 + (r & 63);
  else if (r < 1024) src = ((r - 512) >> 6) * 193 + 64 + (r & 63);
  else if (r < 1536) src = ((r - 1024) >> 6) * 193 + 128 + (r & 63);
  else if (r < 1544) src = (r - 1536) * 193 + 192;
  else               src = -1;
  for (int c = threadIdx.x; c < 512; c += 256)
    d[(size_t)r * 512 + c] = (src >= 0) ? f2bf(s[(size_t)src * 512 + c]) : (u16)0;
}

__global__ __launch_bounds__(64) void conv_x(const float* __restrict__ x,
                                             u16* __restrict__ xbf)
{
  size_t m = blockIdx.x;
  size_t s = m >> 3, b = m & 7;
  const float4* src = (const float4*)(x + (b * (size_t)S_ + s) * HID_);
  float4 v0 = src[threadIdx.x], v1 = src[64 + threadIdx.x];
  u16* dst = xbf + m * HID_;
  uint2 p0, p1;
  p0.x = (unsigned)f2bf(v0.x) | ((unsigned)f2bf(v0.y) << 16);
  p0.y = (unsigned)f2bf(v0.z) | ((unsigned)f2bf(v0.w) << 16);
  p1.x = (unsigned)f2bf(v1.x) | ((unsigned)f2bf(v1.y) << 16);
  p1.y = (unsigned)f2bf(v1.z) | ((unsigned)f2bf(v1.w) << 16);
  *(uint2*)&dst[threadIdx.x * 4] = p0;
  *(uint2*)&dst[256 + threadIdx.x * 4] = p1;
}

__global__ __launch_bounds__(64) void ln_bf(const float* __restrict__ x,
    const float* __restrict__ g, const float* __restrict__ bt,
    u16* __restrict__ o)
{
  size_t row = blockIdx.x;
  int lane = threadIdx.x;
  const float4* xr = (const float4*)(x + row * HID_);
  float4 v0 = xr[lane];
  float4 v1 = xr[64 + lane];
  float s  = v0.x + v0.y + v0.z + v0.w + v1.x + v1.y + v1.z + v1.w;
  float ss = v0.x*v0.x + v0.y*v0.y + v0.z*v0.z + v0.w*v0.w
           + v1.x*v1.x + v1.y*v1.y + v1.z*v1.z + v1.w*v1.w;
  #pragma unroll
  for (int off = 32; off; off >>= 1) {
    s  += __shfl_xor(s, off);
    ss += __shfl_xor(ss, off);
  }
  float mean = s * (1.f / HID_);
  float inv  = rsqrtf(ss * (1.f / HID_) - mean * mean + 1e-5f);
  const float4* gv = (const float4*)g;
  const float4* bv = (const float4*)bt;
  float4 g0 = gv[lane], g1 = gv[64 + lane];
  float4 b0 = bv[lane], b1 = bv[64 + lane];
  uint2 p0, p1;
  p0.x = (unsigned)f2bf((v0.x - mean) * inv * g0.x + b0.x)
       | ((unsigned)f2bf((v0.y - mean) * inv * g0.y + b0.y) << 16);
  p0.y = (unsigned)f2bf((v0.z - mean) * inv * g0.z + b0.z)
       | ((unsigned)f2bf((v0.w - mean) * inv * g0.w + b0.w) << 16);
  p1.x = (unsigned)f2bf((v1.x - mean) * inv * g1.x + b1.x)
       | ((unsigned)f2bf((v1.y - mean) * inv * g1.y + b1.y) << 16);
  p1.y = (unsigned)f2bf((v1.z - mean) * inv * g1.z + b1.z)
       | ((unsigned)f2bf((v1.w - mean) * inv * g1.w + b1.w) << 16);
  u16* ov = o + row * HID_;
  *(uint2*)&ov[lane * 4] = p0;
  *(uint2*)&ov[256 + lane * 4] = p1;
}

// ---------------------------------------------------------------------------
// Delta p1 — R14 structure with A stored TRANSPOSED (AT[col][row]): solve
// reads become wave-uniform ds_read_b128 broadcasts (2 per jj vs 16 scalar).
// Packed b128 stage/output writes; R12 gathered-uint4 CKg epilogue.
// launch_bounds(256,3), no spill.
// ---------------------------------------------------------------------------
__global__ __launch_bounds__(256, 3) void delta_p1(const u16* __restrict__ qf,
                                                   u16* __restrict__ MTg,
                                                   u16* __restrict__ Ng,
                                                   u16* __restrict__ CKg,
                                                   u16* __restrict__ U0Tg)
{
  __shared__ __align__(16) u16 Kb[64 * 72];     // softmaxed K rows
  __shared__ __align__(16) u16 AmKT[64 * 72];   // AT (bf16); post-solve: K^T
  __shared__ __align__(16) u16 stV[16 * 72];    // just-solved block rows (bf16)
  __shared__ __align__(16) u16 stK[16 * 72];
  __shared__ __align__(16) u16 CKTb[64 * 72];
  __shared__ __align__(16) u16 U0Tb[64 * 72];
  __shared__ float bet[64];

  const int id5 = blockIdx.x, bh = id5 >> 5;
  const int b = bh & 7, h = bh >> 3, t0 = (id5 & 31) * 64;
  const int tid = threadIdx.x, lane = tid & 63, wv = tid >> 6;
  const int wid = wv, wrow0 = wv * 16;
  const size_t mb = (size_t)id5 * 4096;

  #pragma unroll
  for (int p = 0; p < 2; ++p) {
    int linear = p * 256 + tid, row = linear >> 3, seg = linear & 7;
    uint4 k4 = *(const uint4*)&qf[((size_t)(t0 + row) * B_ + b) * QN_ + 512 + h * 64 + seg * 8];
    *(short8*)&Kb[row * 72 + seg * 8] = __builtin_bit_cast(short8, k4);
  }
  if (tid < 64) bet[tid] = bf2f(qf[((size_t)(t0 + tid) * B_ + b) * QN_ + 1536 + h]);
  __syncthreads();

  // AT = (beta ⊙ K K^T)^T  (MFMA, transposed element-wise store) -> bf16
  {
    f32x4 a[4] = {};
    prod64<72, 72>(Kb, Kb, wrow0, lane, a);
    #pragma unroll
    for (int c0 = 0; c0 < 4; ++c0)
      #pragma unroll
      for (int j = 0; j < 4; ++j) {
        int row = wrow0 + (lane >> 4) * 4 + j, col = c0 * 16 + (lane & 15);
        AmKT[col * 72 + row] = f2bf(bet[row] * a[c0][j]);   // transposed store
      }
  }

  // per-wave solve state in registers: rows wrow0..+15, column = lane
  float uv[16], uk[16];
  #pragma unroll
  for (int i = 0; i < 16; ++i) {
    const int row = wrow0 + i;
    const float bt_ = bet[row];
    uv[i] = bt_ * bf2f(qf[((size_t)(t0 + row) * B_ + b) * QN_ + 1024 + h * 64 + lane]);
    uk[i] = bt_ * bf2f(Kb[row * 72 + lane]);
  }
  __syncthreads();   // AT ready for all waves

  // blocked forward substitution; A columns read as uniform b128 broadcasts
  #pragma unroll 1
  for (int blk = 0; blk < 4; ++blk) {
    if (wid == blk) {
      const int r0 = blk * 16;
      #pragma unroll
      for (int jj = 0; jj < 15; ++jj) {
        short8 a0 = *(const short8*)&AmKT[(r0 + jj) * 72 + r0];      // A[r0+t][r0+jj], t=0..7
        short8 a1 = *(const short8*)&AmKT[(r0 + jj) * 72 + r0 + 8];  // t=8..15
        float uvj = uv[jj], ukj = uk[jj];
        #pragma unroll
        for (int t = jj + 1; t < 16; ++t) {
          float a = bf2f((u16)(t < 8 ? a0[t] : a1[t - 8]));
          uv[t] = fmaf(-a, uvj, uv[t]);
          uk[t] = fmaf(-a, ukj, uk[t]);
        }
      }
      {
        union { u16 u[16]; short8 s[2]; } pv, pk;
        #pragma unroll
        for (int i = 0; i < 16; ++i) { pv.u[i] = f2bf(uv[i]); pk.u[i] = f2bf(uk[i]); }
        // stage layout transposed: st[col=lane][row i contiguous] for packed writes
        *(short8*)&stV[lane * 18 + 0] = pv.s[0];   // NOTE: see read below
        *(short8*)&stV[lane * 18 + 8] = pv.s[1];
        *(short8*)&stK[lane * 18 + 0] = pk.s[0];
        *(short8*)&stK[lane * 18 + 8] = pk.s[1];
      }
    }
    __syncthreads();
    if (wid > blk) {
      const int r0 = blk * 16;
      #pragma unroll
      for (int jj = 0; jj < 16; ++jj) {
        short8 a0 = *(const short8*)&AmKT[(r0 + jj) * 72 + wrow0];      // A[wrow0+i][r0+jj]
        short8 a1 = *(const short8*)&AmKT[(r0 + jj) * 72 + wrow0 + 8];
        float sv = bf2f(stV[lane * 18 + jj]);
        float sk = bf2f(stK[lane * 18 + jj]);
        #pragma unroll
        for (int i = 0; i < 16; ++i) {
          float a = bf2f((u16)(i < 8 ? a0[i] : a1[i - 8]));
          uv[i] = fmaf(-a, sv, uv[i]);
          uk[i] = fmaf(-a, sk, uk[i]);
        }
      }
    }
    __syncthreads();
  }

  // write CK^T / U0^T to LDS from registers (packed b128)
  {
    union { u16 u[16]; short8 s[2]; } pk, pu;
    #pragma unroll
    for (int i = 0; i < 16; ++i) { pk.u[i] = f2bf(uk[i]); pu.u[i] = f2bf(uv[i]); }
    *(short8*)&CKTb[lane * 72 + wrow0]     = pk.s[0];
    *(short8*)&CKTb[lane * 72 + wrow0 + 8] = pk.s[1];
    *(short8*)&U0Tb[lane * 72 + wrow0]     = pu.s[0];
    *(short8*)&U0Tb[lane * 72 + wrow0 + 8] = pu.s[1];
  }
  // K^T into AmKT (AT dead): gather 16 strided, 2 packed b128 writes
  const int prow = tid >> 2, pc0 = (tid & 3) * 16;
  {
    union { u16 u[16]; short8 s[2]; } pt;
    #pragma unroll
    for (int i = 0; i < 16; ++i) pt.u[i] = Kb[(pc0 + i) * 72 + prow];
    *(short8*)&AmKT[prow * 72 + pc0]     = pt.s[0];
    *(short8*)&AmKT[prow * 72 + pc0 + 8] = pt.s[1];
  }
  __syncthreads();

  // MT = K^T CK, N = U0^T K (MFMA); gathered coalesced global writes
  {
    f32x4 am[4] = {}, an[4] = {};
    prod64<72, 72>(AmKT, CKTb, wrow0, lane, am);
    prod64<72, 72>(U0Tb, AmKT, wrow0, lane, an);
    #pragma unroll
    for (int c0 = 0; c0 < 4; ++c0)
      #pragma unroll
      for (int j = 0; j < 4; ++j) {
        int row = wrow0 + (lane >> 4) * 4 + j, col = c0 * 16 + (lane & 15);
        MTg[mb + (size_t)row * 64 + col] = f2bf(am[c0][j]);
        Ng[mb + (size_t)row * 64 + col]  = f2bf(an[c0][j]);
      }
    // CKg[t][d] gathered from CKTb (transpose), coalesced uint4 stores
    union { u16 u[16]; uint4 v[2]; } pc;
    #pragma unroll
    for (int i = 0; i < 16; ++i) pc.u[i] = CKTb[(pc0 + i) * 72 + prow];
    *(uint4*)&CKg[mb + prow * 64 + pc0]     = pc.v[0];
    *(uint4*)&CKg[mb + prow * 64 + pc0 + 8] = pc.v[1];
    short8 a0 = *(const short8*)&U0Tb[prow * 72 + pc0];
    short8 a1 = *(const short8*)&U0Tb[prow * 72 + pc0 + 8];
    *(uint4*)&U0Tg[mb + prow * 64 + pc0]     = __builtin_bit_cast(uint4, a0);
    *(uint4*)&U0Tg[mb + prow * 64 + pc0 + 8] = __builtin_bit_cast(uint4, a1);
  }
}

__global__ __launch_bounds__(256, 1) void delta_p2(const u16* __restrict__ MTg,
                                                   const u16* __restrict__ Ng,
                                                   u16* __restrict__ Wsnap)
{
  __shared__ float Ws[64][65];
  __shared__ __align__(16) u16 Wbf[64 * 72];
  __shared__ __align__(16) u16 MTb[64 * 72];
  __shared__ __align__(16) u16 Nb[64 * 72];
  const int bh = blockIdx.x;
  const int tid = threadIdx.x, lane = tid & 63, wv = tid >> 6, wrow0 = wv * 16;
  const int prow = tid >> 2, pc0 = (tid & 3) * 16;

  for (int i = tid; i < 64 * 65; i += 256) (&Ws[0][0])[i] = 0.f;
  for (int i = tid; i < 64 * 72; i += 256) Wbf[i] = 0;
  __syncthreads();

  size_t base = (size_t)bh * NCH_ * 4096;
  uint4 rm0 = *(const uint4*)&MTg[base + prow * 64 + pc0];
  uint4 rm1 = *(const uint4*)&MTg[base + prow * 64 + pc0 + 8];
  uint4 rn0 = *(const uint4*)&Ng[base + prow * 64 + pc0];
  uint4 rn1 = *(const uint4*)&Ng[base + prow * 64 + pc0 + 8];

  for (int j = 0; j < NCH_; ++j) {
    *(short8*)&MTb[prow * 72 + pc0]     = __builtin_bit_cast(short8, rm0);
    *(short8*)&MTb[prow * 72 + pc0 + 8] = __builtin_bit_cast(short8, rm1);
    *(short8*)&Nb[prow * 72 + pc0]      = __builtin_bit_cast(short8, rn0);
    *(short8*)&Nb[prow * 72 + pc0 + 8]  = __builtin_bit_cast(short8, rn1);
    {
      size_t sb = base + (size_t)j * 4096;
      short8 w0 = *(const short8*)&Wbf[prow * 72 + pc0];
      short8 w1 = *(const short8*)&Wbf[prow * 72 + pc0 + 8];
      *(uint4*)&Wsnap[sb + prow * 64 + pc0]     = __builtin_bit_cast(uint4, w0);
      *(uint4*)&Wsnap[sb + prow * 64 + pc0 + 8] = __builtin_bit_cast(uint4, w1);
    }
    if (j + 1 < NCH_) {
      size_t nb2 = base + (size_t)(j + 1) * 4096;
      rm0 = *(const uint4*)&MTg[nb2 + prow * 64 + pc0];
      rm1 = *(const uint4*)&MTg[nb2 + prow * 64 + pc0 + 8];
      rn0 = *(const uint4*)&Ng[nb2 + prow * 64 + pc0];
      rn1 = *(const uint4*)&Ng[nb2 + prow * 64 + pc0 + 8];
    }
    __syncthreads();
    f32x4 a[4] = {};
    prod64<72, 72>(Wbf, MTb, wrow0, lane, a);
    #pragma unroll
    for (int c0 = 0; c0 < 4; ++c0)
      #pragma unroll
      for (int jj = 0; jj < 4; ++jj) {
        int row = wrow0 + (lane >> 4) * 4 + jj, col = c0 * 16 + (lane & 15);
        float w = Ws[row][col] + bf2f(Nb[row * 72 + col]) - a[c0][jj];
        Ws[row][col] = w;
        Wbf[row * 72 + col] = f2bf(w);
      }
    __syncthreads();
  }
}

__global__ __launch_bounds__(256, 2) void delta_p3(const u16* __restrict__ qf,
                                                   const u16* __restrict__ Wsnap,
                                                   const u16* __restrict__ CKg,
                                                   const u16* __restrict__ U0Tg,
                                                   u16* __restrict__ attnb)
{
  __shared__ __align__(16) u16 Qb[64 * 72];
  __shared__ __align__(16) u16 Kb[64 * 72];
  __shared__ __align__(16) u16 W0b[64 * 72];
  __shared__ __align__(16) u16 CKb[64 * 72];
  __shared__ __align__(16) u16 U0Tb[64 * 72];
  __shared__ __align__(16) u16 Gb[64 * 72];
  __shared__ __align__(16) u16 UTb[64 * 72];

  const int id5 = blockIdx.x, bh = id5 >> 5;
  const int b = bh & 7, h = bh >> 3, t0 = (id5 & 31) * 64;
  const int tid = threadIdx.x, lane = tid & 63, wv = tid >> 6, wrow0 = wv * 16;
  const int prow = tid >> 2, pc0 = (tid & 3) * 16;
  const size_t mb = (size_t)id5 * 4096;

  #pragma unroll
  for (int p = 0; p < 2; ++p) {
    int linear = p * 256 + tid, row = linear >> 3, seg = linear & 7;
    size_t gb = ((size_t)(t0 + row) * B_ + b) * QN_;
    uint4 q4 = *(const uint4*)&qf[gb + h * 64 + seg * 8];
    uint4 k4 = *(const uint4*)&qf[gb + 512 + h * 64 + seg * 8];
    uint4 w4 = *(const uint4*)&Wsnap[mb + (size_t)row * 64 + seg * 8];
    *(short8*)&Qb[row * 72 + seg * 8]  = __builtin_bit_cast(short8, q4);
    *(short8*)&Kb[row * 72 + seg * 8]  = __builtin_bit_cast(short8, k4);
    *(short8*)&W0b[row * 72 + seg * 8] = __builtin_bit_cast(short8, w4);
  }
  {
    uint4 c0v = *(const uint4*)&CKg[mb + prow * 64 + pc0];
    uint4 c1v = *(const uint4*)&CKg[mb + prow * 64 + pc0 + 8];
    uint4 u0v = *(const uint4*)&U0Tg[mb + prow * 64 + pc0];
    uint4 u1v = *(const uint4*)&U0Tg[mb + prow * 64 + pc0 + 8];
    *(short8*)&CKb[prow * 72 + pc0]      = __builtin_bit_cast(short8, c0v);
    *(short8*)&CKb[prow * 72 + pc0 + 8]  = __builtin_bit_cast(short8, c1v);
    *(short8*)&U0Tb[prow * 72 + pc0]     = __builtin_bit_cast(short8, u0v);
    *(short8*)&U0Tb[prow * 72 + pc0 + 8] = __builtin_bit_cast(short8, u1v);
  }
  __syncthreads();

  f32x4 ag[4] = {}, ac[4] = {}, ab[4] = {};
  prod64<72, 72>(Qb, Kb, wrow0, lane, ag);    // QK^T
  prod64<72, 72>(W0b, CKb, wrow0, lane, ac);  // (W0·CK^T)[d][t]
  prod64<72, 72>(Qb, W0b, wrow0, lane, ab);   // Q·W0^T

  #pragma unroll
  for (int c0 = 0; c0 < 4; ++c0)
    #pragma unroll
    for (int j = 0; j < 4; ++j) {
      int row = wrow0 + (lane >> 4) * 4 + j, col = c0 * 16 + (lane & 15);
      Gb[row * 72 + col]  = f2bf(col <= row ? ag[c0][j] : 0.f);
      UTb[row * 72 + col] = f2bf(bf2f(U0Tb[row * 72 + col]) - ac[c0][j]);
    }
  __syncthreads();

  prod64<72, 72>(Gb, UTb, wrow0, lane, ab);   // += G·U

  #pragma unroll
  for (int c0 = 0; c0 < 4; ++c0)
    #pragma unroll
    for (int j = 0; j < 4; ++j) {
      int row = wrow0 + (lane >> 4) * 4 + j, col = c0 * 16 + (lane & 15);
      attnb[((size_t)(t0 + row) * B_ + b) * HID_ + h * 64 + col] = f2bf(ab[c0][j]);
    }
}

// ---------------------------------------------------------------------------
extern "C" void kernel_launch(void* const* d_in, const int* in_sizes, int n_in,
                              void* d_out, int out_size, void* d_ws, size_t ws_size,
                              hipStream_t stream)
{
  const float* x        = (const float*)d_in[0];
  const float* ip_w     = (const float*)d_in[1];
  const float* ip_b     = (const float*)d_in[2];
  const float* fw_ln_g  = (const float*)d_in[3];
  const float* fw_ln_b  = (const float*)d_in[4];
  const float* fw_slow_w = (const float*)d_in[5];
  const float* fw_out_w  = (const float*)d_in[6];
  const float* ff_ln_g  = (const float*)d_in[7];
  const float* ff_ln_b  = (const float*)d_in[8];
  const float* ff_w1    = (const float*)d_in[9];
  const float* ff_b1    = (const float*)d_in[10];
  const float* ff_w2    = (const float*)d_in[11];
  const float* ff_b2    = (const float*)d_in[12];
  float* out = (float*)d_out;

  const int M = B_ * S_;  // 16384
  const size_t matN = (size_t)64 * NCH_ * 4096;   // 8.39M elems

  const size_t nIp = 512 * 512, nOut = 512 * 512;
  const size_t nSlow = (size_t)QN_ * 512;
  const size_t nW1 = (size_t)FF_ * 512, nW2 = (size_t)512 * FF_;
  const size_t nXbf = (size_t)M * HID_;
  const size_t poolElems = nIp + 2 * nSlow + 2 * nOut + nW1 + nW2 + nXbf + matN;

  size_t need = (size_t)M * HID_ * 4
              + ((size_t)M * QN_ + 2 * matN + poolElems) * 2;
  if (ws_size < need) return;

  float* cur   = (float*)d_ws;
  u16*   qkvbf = (u16*)(cur + (size_t)M * HID_);            // [M][1664] bf16
  u16*   attnSlot = qkvbf + (size_t)M * QN_;                // 2*matN u16
  u16*   MTg   = attnSlot;
  u16*   Ng    = MTg + matN;
  u16*   attnb = attnSlot;                                  // reuses MTg after p2
  u16*   CKg   = (u16*)out;
  u16*   U0Tg  = CKg + matN;
  u16*   tmpbf = (u16*)out;                                 // LN out; dead when CKg live
  u16*   hiddenb = qkvbf;                                   // FFN hidden

  u16* pool = attnSlot + 2 * matN;
  u16* ipwb   = pool;               pool += nIp;
  u16* slowb0 = pool;               pool += nSlow;
  u16* slowb1 = pool;               pool += nSlow;
  u16* outwb0 = pool;               pool += nOut;
  u16* outwb1 = pool;               pool += nOut;
  u16* w1b    = pool;               pool += nW1;
  u16* w2b    = pool;               pool += nW2;
  u16* Wsnap  = pool;               pool += matN;
  u16* xbf    = pool;

  dim3 blk(256);

  conv_w<<<(nIp + 255) / 256, blk, 0, stream>>>(ip_w, ipwb, nIp, nIp);
  conv_slow<<<QN_, blk, 0, stream>>>(fw_slow_w, slowb0);
  conv_slow<<<QN_, blk, 0, stream>>>(fw_slow_w + (size_t)SLOWSTRIDE, slowb1);
  conv_w<<<(nOut + 255) / 256, blk, 0, stream>>>(fw_out_w, outwb0, nOut, nOut);
  conv_w<<<(nOut + 255) / 256, blk, 0, stream>>>(fw_out_w + (size_t)512 * 512, outwb1, nOut, nOut);
  conv_w<<<(nW1 + 255) / 256, blk, 0, stream>>>(ff_w1, w1b, nW1, nW1);
  conv_w<<<(nW2 + 255) / 256, blk, 0, stream>>>(ff_w2, w2b, nW2, nW2);
  conv_x<<<M, 64, 0, stream>>>(x, xbf);

  gemm_bf<true, false, false, false, false, false><<<4 * 128, blk, 0, stream>>>(
      xbf, ipwb, ip_b, nullptr, cur, M, HID_, HID_, 4);

  for (int layer = 0; layer < 2; ++layer) {
    u16* slowb = layer ? slowb1 : slowb0;
    u16* outwb = layer ? outwb1 : outwb0;

    ln_bf<<<M, 64, 0, stream>>>(cur, fw_ln_g + layer * HID_, fw_ln_b + layer * HID_, tmpbf);
    gemm_bf<false, false, false, true, false, true><<<13 * 128, blk, 0, stream>>>(
        tmpbf, slowb, nullptr, nullptr, qkvbf, M, QN_, HID_, 13);
    delta_p1<<<64 * NCH_, 256, 0, stream>>>(qkvbf, MTg, Ng, CKg, U0Tg);
    delta_p2<<<64, 256, 0, stream>>>(MTg, Ng, Wsnap);
    delta_p3<<<64 * NCH_, 256, 0, stream>>>(qkvbf, Wsnap, CKg, U0Tg, attnb);
    if (layer == 0) {
      gemm_bf<false, false, true, false, false, false><<<4 * 128, blk, 0, stream>>>(
          attnb, outwb, nullptr, cur, cur, M, HID_, HID_, 4);
      ln_bf<<<M, 64, 0, stream>>>(cur, ff_ln_g, ff_ln_b, tmpbf);
      gemm_bf<true, true, false, true, false, false><<<16 * 128, blk, 0, stream>>>(
          tmpbf, w1b, ff_b1, nullptr, hiddenb, M, FF_, HID_, 16);
      gemm_bf<true, false, true, false, false, false><<<4 * 128, blk, 0, stream>>>(
          hiddenb, w2b, ff_b2, cur, cur, M, HID_, FF_, 4);
    } else {
      // final out-proj writes [B,S,512] directly (fused transpose)
      gemm_bf<false, false, true, false, true, false><<<4 * 128, blk, 0, stream>>>(
          attnb, outwb, nullptr, cur, out, M, HID_, HID_, 4);
    }
  }
}

// Round 16
// 472.324 us; speedup vs baseline: 1.1048x; 1.1048x over previous
//
#include <hip/hip_runtime.h>
#include <hip/hip_bf16.h>

#define B_    8
#define S_    2048
#define HID_  512
#define H_    8
#define D_    64
#define FF_   2048
#define QN_   1664   // padded qkvb width: q 512 | k 512 | v 512 | beta 8 (pad 128)
#define NCH_  32     // S/64 chunks
#define SLOWSTRIDE (1544 * 512)   // fw_slow_w per-layer stride (floats)

typedef unsigned short u16;
typedef __attribute__((ext_vector_type(8))) short short8;
typedef __attribute__((ext_vector_type(4))) float f32x4;

__device__ __forceinline__ u16 f2bf(float x) {           // RNE fp32->bf16
  unsigned u = __builtin_bit_cast(unsigned, x);
  unsigned r = (u + 0x7FFFu + ((u >> 16) & 1u)) >> 16;
  return (u16)r;
}
__device__ __forceinline__ float bf2f(u16 v) {
  return __builtin_bit_cast(float, (unsigned)v << 16);
}
__device__ __forceinline__ void gload16(const void* g, void* l) {
  __builtin_amdgcn_global_load_lds(
      (const __attribute__((address_space(1))) unsigned int*)g,
      (__attribute__((address_space(3))) unsigned int*)l, 16, 0, 0);
}

// 64x64x64 product C[r][c] = sum_k F[r][k]*G[c][k], bf16 LDS operands.
template<int FS, int GS>
__device__ __forceinline__ void prod64(const u16* __restrict__ F,
                                       const u16* __restrict__ G,
                                       int wrow0, int lane, f32x4 acc[4])
{
  short8 f0 = *(const short8*)&F[(wrow0 + (lane & 15)) * FS + ((lane >> 4) * 8)];
  short8 f1 = *(const short8*)&F[(wrow0 + (lane & 15)) * FS + 32 + ((lane >> 4) * 8)];
  #pragma unroll
  for (int c0 = 0; c0 < 4; ++c0) {
    short8 g0 = *(const short8*)&G[(c0 * 16 + (lane & 15)) * GS + ((lane >> 4) * 8)];
    short8 g1 = *(const short8*)&G[(c0 * 16 + (lane & 15)) * GS + 32 + ((lane >> 4) * 8)];
    acc[c0] = __builtin_amdgcn_mfma_f32_16x16x32_bf16(f0, g0, acc[c0], 0, 0, 0);
    acc[c0] = __builtin_amdgcn_mfma_f32_16x16x32_bf16(f1, g1, acc[c0], 0, 0, 0);
  }
}

// ---------------------------------------------------------------------------
// bf16 GEMM: BK=32 double-buffered gload_lds staging, both-sides swizzle,
// 4-pass LDS-staged epilogue, XCD-aware block swizzle (1D grid, %8==0).
// ---------------------------------------------------------------------------
template<bool BIAS, bool RELU, bool RES, bool OUTBF, bool TRANS, bool QKVB>
__global__ __launch_bounds__(256, 4) void gemm_bf(
    const u16* __restrict__ A, const u16* __restrict__ W,
    const float* __restrict__ bias, const float* __restrict__ res,
    void* __restrict__ Cout, int M, int N, int K, int nx)
{
  __shared__ __align__(16) u16 SH[16384];   // 32KB: [As0|Bs0|As1|Bs1]
  const int tid = threadIdx.x, lane = tid & 63, wv = tid >> 6;
  const int nwg = gridDim.x;
  const int l = ((blockIdx.x & 7) * (nwg >> 3)) + (blockIdx.x >> 3);
  const int bm = (l / nx) * 128, bn = (l % nx) * 128;
  const int wr = wv >> 1, wc = wv & 1;
  const int row16 = lane & 15, kg = lane >> 4;
  const int srow = lane >> 2;
  const int ssoff = ((lane & 3) ^ (srow & 3)) * 16;

  f32x4 acc[4][4] = {};
  const int ktiles = K >> 5;

  auto STAGE = [&](int buf, int kt) {
    u16* As = &SH[buf * 8192];
    u16* Bs = &SH[buf * 8192 + 4096];
    #pragma unroll
    for (int i = 0; i < 2; ++i) {
      const int r = i * 64 + wv * 16;
      const char* ga = (const char*)(A + (size_t)(bm + r + srow) * K + (size_t)kt * 32) + ssoff;
      gload16(ga, &As[r * 32]);
      const char* gw = (const char*)(W + (size_t)(bn + r + srow) * K + (size_t)kt * 32) + ssoff;
      gload16(gw, &Bs[r * 32]);
    }
  };

  STAGE(0, 0);
  __syncthreads();
  int buf = 0;
  for (int kt = 0; kt < ktiles; ++kt) {
    if (kt + 1 < ktiles) STAGE(buf ^ 1, kt + 1);
    const u16* As = &SH[buf * 8192];
    const u16* Bs = &SH[buf * 8192 + 4096];
    short8 af[4], bf_[4];
    #pragma unroll
    for (int m = 0; m < 4; ++m) {
      const int lrow = wr * 64 + m * 16 + row16;
      af[m] = *(const short8*)&As[lrow * 32 + (kg ^ (lrow & 3)) * 8];
    }
    #pragma unroll
    for (int n = 0; n < 4; ++n) {
      const int lrow = wc * 64 + n * 16 + row16;
      bf_[n] = *(const short8*)&Bs[lrow * 32 + (kg ^ (lrow & 3)) * 8];
    }
    #pragma unroll
    for (int m = 0; m < 4; ++m)
      #pragma unroll
      for (int n = 0; n < 4; ++n)
        acc[m][n] = __builtin_amdgcn_mfma_f32_16x16x32_bf16(af[m], bf_[n], acc[m][n], 0, 0, 0);
    __syncthreads();
    buf ^= 1;
  }

  if (QKVB) {
    const int span0 = bn + wc * 64;
    #pragma unroll
    for (int m = 0; m < 4; ++m) {
      #pragma unroll
      for (int j = 0; j < 4; ++j) {
        if (span0 < 1024) {
          float v0 = acc[m][0][j], v1 = acc[m][1][j];
          float v2 = acc[m][2][j], v3 = acc[m][3][j];
          float mx = fmaxf(fmaxf(v0, v1), fmaxf(v2, v3));
          #pragma unroll
          for (int off = 1; off < 16; off <<= 1) mx = fmaxf(mx, __shfl_xor(mx, off));
          float e0 = __expf(v0 - mx), e1 = __expf(v1 - mx);
          float e2 = __expf(v2 - mx), e3 = __expf(v3 - mx);
          float s = (e0 + e1) + (e2 + e3);
          #pragma unroll
          for (int off = 1; off < 16; off <<= 1) s += __shfl_xor(s, off);
          float r = 1.f / s;
          acc[m][0][j] = e0 * r; acc[m][1][j] = e1 * r;
          acc[m][2][j] = e2 * r; acc[m][3][j] = e3 * r;
        } else if (span0 >= 1536) {
          #pragma unroll
          for (int n = 0; n < 4; ++n)
            acc[m][n][j] = 1.f / (1.f + __expf(-acc[m][n][j]));
        }
      }
    }
  }

  float* LD = (float*)SH;
  #pragma unroll
  for (int p = 0; p < 4; ++p) {
    if (p) __syncthreads();
    if (wr == (p >> 1)) {
      #pragma unroll
      for (int mm = 0; mm < 2; ++mm) {
        const int m = (p & 1) * 2 + mm;
        #pragma unroll
        for (int n = 0; n < 4; ++n)
          #pragma unroll
          for (int j = 0; j < 4; ++j)
            LD[(mm * 16 + kg * 4 + j) * 132 + wc * 64 + n * 16 + row16] = acc[m][n][j];
      }
    }
    __syncthreads();
    #pragma unroll
    for (int step = 0; step < 4; ++step) {
      int linear = step * 256 + tid;
      int row = linear >> 5, q = linear & 31;
      float4 v = *(const float4*)&LD[row * 132 + q * 4];
      const int grow = bm + p * 32 + row;
      const int gcol = bn + q * 4;
      if (BIAS) {
        float4 b4 = *(const float4*)&bias[gcol];
        v.x += b4.x; v.y += b4.y; v.z += b4.z; v.w += b4.w;
      }
      if (RES) {
        float4 r4 = *(const float4*)&res[(size_t)grow * N + gcol];
        v.x += r4.x; v.y += r4.y; v.z += r4.z; v.w += r4.w;
      }
      if (RELU) {
        v.x = fmaxf(v.x, 0.f); v.y = fmaxf(v.y, 0.f);
        v.z = fmaxf(v.z, 0.f); v.w = fmaxf(v.w, 0.f);
      }
      size_t gr = TRANS ? ((size_t)(grow & 7) * S_ + (grow >> 3)) : (size_t)grow;
      if (OUTBF) {
        uint2 pk;
        pk.x = (unsigned)f2bf(v.x) | ((unsigned)f2bf(v.y) << 16);
        pk.y = (unsigned)f2bf(v.z) | ((unsigned)f2bf(v.w) << 16);
        *(uint2*)&((u16*)Cout)[gr * N + gcol] = pk;
      } else {
        *(float4*)&((float*)Cout)[gr * N + gcol] = v;
      }
    }
  }
}

// ---------------------------------------------------------------------------
// Merged weight conversion: one launch for all weights.
// segments: ipw 1024 | slow0 1664 | slow1 1664 | outw0 1024 | outw1 1024 |
//           w1 4096 | w2 4096   => grid 14592
// ---------------------------------------------------------------------------
__global__ __launch_bounds__(256) void conv_all(
    const float* __restrict__ ip_w, const float* __restrict__ slow_w,
    const float* __restrict__ out_w, const float* __restrict__ w1,
    const float* __restrict__ w2,
    u16* __restrict__ ipwb, u16* __restrict__ slowb0, u16* __restrict__ slowb1,
    u16* __restrict__ outwb0, u16* __restrict__ outwb1,
    u16* __restrict__ w1b, u16* __restrict__ w2b)
{
  int bid = blockIdx.x;
  const int tid = threadIdx.x;
  if (bid < 1024) {
    int i = bid * 256 + tid;
    ipwb[i] = f2bf(ip_w[i]);
    return;
  }
  bid -= 1024;
  if (bid < 2 * QN_) {
    int layer = bid / QN_, r = bid % QN_;
    const float* s = slow_w + (size_t)layer * SLOWSTRIDE;
    u16* d = (layer ? slowb1 : slowb0);
    int src;
    if (r < 512)       src = (r >> 6) * 193 + (r & 63);
    else if (r < 1024) src = ((r - 512) >> 6) * 193 + 64 + (r & 63);
    else if (r < 1536) src = ((r - 1024) >> 6) * 193 + 128 + (r & 63);
    else if (r < 1544) src = (r - 1536) * 193 + 192;
    else               src = -1;
    for (int c = tid; c < 512; c += 256)
      d[(size_t)r * 512 + c] = (src >= 0) ? f2bf(s[(size_t)src * 512 + c]) : (u16)0;
    return;
  }
  bid -= 2 * QN_;
  if (bid < 2048) {
    int layer = bid >> 10;
    int i = (bid & 1023) * 256 + tid;
    (layer ? outwb1 : outwb0)[i] = f2bf(out_w[(size_t)layer * 262144 + i]);
    return;
  }
  bid -= 2048;
  if (bid < 4096) {
    int i = bid * 256 + tid;
    w1b[i] = f2bf(w1[i]);
    return;
  }
  bid -= 4096;
  {
    int i = bid * 256 + tid;
    w2b[i] = f2bf(w2[i]);
  }
}

__global__ __launch_bounds__(64) void conv_x(const float* __restrict__ x,
                                             u16* __restrict__ xbf)
{
  size_t m = blockIdx.x;
  size_t s = m >> 3, b = m & 7;
  const float4* src = (const float4*)(x + (b * (size_t)S_ + s) * HID_);
  float4 v0 = src[threadIdx.x], v1 = src[64 + threadIdx.x];
  u16* dst = xbf + m * HID_;
  uint2 p0, p1;
  p0.x = (unsigned)f2bf(v0.x) | ((unsigned)f2bf(v0.y) << 16);
  p0.y = (unsigned)f2bf(v0.z) | ((unsigned)f2bf(v0.w) << 16);
  p1.x = (unsigned)f2bf(v1.x) | ((unsigned)f2bf(v1.y) << 16);
  p1.y = (unsigned)f2bf(v1.z) | ((unsigned)f2bf(v1.w) << 16);
  *(uint2*)&dst[threadIdx.x * 4] = p0;
  *(uint2*)&dst[256 + threadIdx.x * 4] = p1;
}

__global__ __launch_bounds__(64) void ln_bf(const float* __restrict__ x,
    const float* __restrict__ g, const float* __restrict__ bt,
    u16* __restrict__ o)
{
  size_t row = blockIdx.x;
  int lane = threadIdx.x;
  const float4* xr = (const float4*)(x + row * HID_);
  float4 v0 = xr[lane];
  float4 v1 = xr[64 + lane];
  float s  = v0.x + v0.y + v0.z + v0.w + v1.x + v1.y + v1.z + v1.w;
  float ss = v0.x*v0.x + v0.y*v0.y + v0.z*v0.z + v0.w*v0.w
           + v1.x*v1.x + v1.y*v1.y + v1.z*v1.z + v1.w*v1.w;
  #pragma unroll
  for (int off = 32; off; off >>= 1) {
    s  += __shfl_xor(s, off);
    ss += __shfl_xor(ss, off);
  }
  float mean = s * (1.f / HID_);
  float inv  = rsqrtf(ss * (1.f / HID_) - mean * mean + 1e-5f);
  const float4* gv = (const float4*)g;
  const float4* bv = (const float4*)bt;
  float4 g0 = gv[lane], g1 = gv[64 + lane];
  float4 b0 = bv[lane], b1 = bv[64 + lane];
  uint2 p0, p1;
  p0.x = (unsigned)f2bf((v0.x - mean) * inv * g0.x + b0.x)
       | ((unsigned)f2bf((v0.y - mean) * inv * g0.y + b0.y) << 16);
  p0.y = (unsigned)f2bf((v0.z - mean) * inv * g0.z + b0.z)
       | ((unsigned)f2bf((v0.w - mean) * inv * g0.w + b0.w) << 16);
  p1.x = (unsigned)f2bf((v1.x - mean) * inv * g1.x + b1.x)
       | ((unsigned)f2bf((v1.y - mean) * inv * g1.y + b1.y) << 16);
  p1.y = (unsigned)f2bf((v1.z - mean) * inv * g1.z + b1.z)
       | ((unsigned)f2bf((v1.w - mean) * inv * g1.w + b1.w) << 16);
  u16* ov = o + row * HID_;
  *(uint2*)&ov[lane * 4] = p0;
  *(uint2*)&ov[256 + lane * 4] = p1;
}

// ---------------------------------------------------------------------------
// Delta p1 — R15 structure (AT broadcasts), launch_bounds(256,3), no spill.
// ---------------------------------------------------------------------------
__global__ __launch_bounds__(256, 3) void delta_p1(const u16* __restrict__ qf,
                                                   u16* __restrict__ MTg,
                                                   u16* __restrict__ Ng,
                                                   u16* __restrict__ CKg,
                                                   u16* __restrict__ U0Tg)
{
  __shared__ __align__(16) u16 Kb[64 * 72];     // softmaxed K rows
  __shared__ __align__(16) u16 AmKT[64 * 72];   // AT (bf16); post-solve: K^T
  __shared__ __align__(16) u16 stV[16 * 72];
  __shared__ __align__(16) u16 stK[16 * 72];
  __shared__ __align__(16) u16 CKTb[64 * 72];
  __shared__ __align__(16) u16 U0Tb[64 * 72];
  __shared__ float bet[64];

  const int id5 = blockIdx.x, bh = id5 >> 5;
  const int b = bh & 7, h = bh >> 3, t0 = (id5 & 31) * 64;
  const int tid = threadIdx.x, lane = tid & 63, wv = tid >> 6;
  const int wid = wv, wrow0 = wv * 16;
  const size_t mb = (size_t)id5 * 4096;

  #pragma unroll
  for (int p = 0; p < 2; ++p) {
    int linear = p * 256 + tid, row = linear >> 3, seg = linear & 7;
    uint4 k4 = *(const uint4*)&qf[((size_t)(t0 + row) * B_ + b) * QN_ + 512 + h * 64 + seg * 8];
    *(short8*)&Kb[row * 72 + seg * 8] = __builtin_bit_cast(short8, k4);
  }
  if (tid < 64) bet[tid] = bf2f(qf[((size_t)(t0 + tid) * B_ + b) * QN_ + 1536 + h]);
  __syncthreads();

  {
    f32x4 a[4] = {};
    prod64<72, 72>(Kb, Kb, wrow0, lane, a);
    #pragma unroll
    for (int c0 = 0; c0 < 4; ++c0)
      #pragma unroll
      for (int j = 0; j < 4; ++j) {
        int row = wrow0 + (lane >> 4) * 4 + j, col = c0 * 16 + (lane & 15);
        AmKT[col * 72 + row] = f2bf(bet[row] * a[c0][j]);   // transposed store
      }
  }

  float uv[16], uk[16];
  #pragma unroll
  for (int i = 0; i < 16; ++i) {
    const int row = wrow0 + i;
    const float bt_ = bet[row];
    uv[i] = bt_ * bf2f(qf[((size_t)(t0 + row) * B_ + b) * QN_ + 1024 + h * 64 + lane]);
    uk[i] = bt_ * bf2f(Kb[row * 72 + lane]);
  }
  __syncthreads();

  #pragma unroll 1
  for (int blk = 0; blk < 4; ++blk) {
    if (wid == blk) {
      const int r0 = blk * 16;
      #pragma unroll
      for (int jj = 0; jj < 15; ++jj) {
        short8 a0 = *(const short8*)&AmKT[(r0 + jj) * 72 + r0];
        short8 a1 = *(const short8*)&AmKT[(r0 + jj) * 72 + r0 + 8];
        float uvj = uv[jj], ukj = uk[jj];
        #pragma unroll
        for (int t = jj + 1; t < 16; ++t) {
          float a = bf2f((u16)(t < 8 ? a0[t] : a1[t - 8]));
          uv[t] = fmaf(-a, uvj, uv[t]);
          uk[t] = fmaf(-a, ukj, uk[t]);
        }
      }
      {
        union { u16 u[16]; short8 s[2]; } pv, pk;
        #pragma unroll
        for (int i = 0; i < 16; ++i) { pv.u[i] = f2bf(uv[i]); pk.u[i] = f2bf(uk[i]); }
        *(short8*)&stV[lane * 18 + 0] = pv.s[0];
        *(short8*)&stV[lane * 18 + 8] = pv.s[1];
        *(short8*)&stK[lane * 18 + 0] = pk.s[0];
        *(short8*)&stK[lane * 18 + 8] = pk.s[1];
      }
    }
    __syncthreads();
    if (wid > blk) {
      const int r0 = blk * 16;
      #pragma unroll
      for (int jj = 0; jj < 16; ++jj) {
        short8 a0 = *(const short8*)&AmKT[(r0 + jj) * 72 + wrow0];
        short8 a1 = *(const short8*)&AmKT[(r0 + jj) * 72 + wrow0 + 8];
        float sv = bf2f(stV[lane * 18 + jj]);
        float sk = bf2f(stK[lane * 18 + jj]);
        #pragma unroll
        for (int i = 0; i < 16; ++i) {
          float a = bf2f((u16)(i < 8 ? a0[i] : a1[i - 8]));
          uv[i] = fmaf(-a, sv, uv[i]);
          uk[i] = fmaf(-a, sk, uk[i]);
        }
      }
    }
    __syncthreads();
  }

  {
    union { u16 u[16]; short8 s[2]; } pk, pu;
    #pragma unroll
    for (int i = 0; i < 16; ++i) { pk.u[i] = f2bf(uk[i]); pu.u[i] = f2bf(uv[i]); }
    *(short8*)&CKTb[lane * 72 + wrow0]     = pk.s[0];
    *(short8*)&CKTb[lane * 72 + wrow0 + 8] = pk.s[1];
    *(short8*)&U0Tb[lane * 72 + wrow0]     = pu.s[0];
    *(short8*)&U0Tb[lane * 72 + wrow0 + 8] = pu.s[1];
  }
  const int prow = tid >> 2, pc0 = (tid & 3) * 16;
  {
    union { u16 u[16]; short8 s[2]; } pt;
    #pragma unroll
    for (int i = 0; i < 16; ++i) pt.u[i] = Kb[(pc0 + i) * 72 + prow];
    *(short8*)&AmKT[prow * 72 + pc0]     = pt.s[0];
    *(short8*)&AmKT[prow * 72 + pc0 + 8] = pt.s[1];
  }
  __syncthreads();

  {
    f32x4 am[4] = {}, an[4] = {};
    prod64<72, 72>(AmKT, CKTb, wrow0, lane, am);
    prod64<72, 72>(U0Tb, AmKT, wrow0, lane, an);
    #pragma unroll
    for (int c0 = 0; c0 < 4; ++c0)
      #pragma unroll
      for (int j = 0; j < 4; ++j) {
        int row = wrow0 + (lane >> 4) * 4 + j, col = c0 * 16 + (lane & 15);
        MTg[mb + (size_t)row * 64 + col] = f2bf(am[c0][j]);
        Ng[mb + (size_t)row * 64 + col]  = f2bf(an[c0][j]);
      }
    union { u16 u[16]; uint4 v[2]; } pc;
    #pragma unroll
    for (int i = 0; i < 16; ++i) pc.u[i] = CKTb[(pc0 + i) * 72 + prow];
    *(uint4*)&CKg[mb + prow * 64 + pc0]     = pc.v[0];
    *(uint4*)&CKg[mb + prow * 64 + pc0 + 8] = pc.v[1];
    short8 a0 = *(const short8*)&U0Tb[prow * 72 + pc0];
    short8 a1 = *(const short8*)&U0Tb[prow * 72 + pc0 + 8];
    *(uint4*)&U0Tg[mb + prow * 64 + pc0]     = __builtin_bit_cast(uint4, a0);
    *(uint4*)&U0Tg[mb + prow * 64 + pc0 + 8] = __builtin_bit_cast(uint4, a1);
  }
}

// ---------------------------------------------------------------------------
// Delta p2, row-split 4x: block = bh*4 + rg handles 16 rows of W.
// W rows evolve independently: W16_{j+1} = W16_j (I - M_j) + N16_j.
// ---------------------------------------------------------------------------
__global__ __launch_bounds__(256, 2) void delta_p2(const u16* __restrict__ MTg,
                                                   const u16* __restrict__ Ng,
                                                   u16* __restrict__ Wsnap)
{
  __shared__ __align__(16) u16 MTb[64 * 72];
  __shared__ __align__(16) u16 Nb[16 * 72];
  __shared__ __align__(16) u16 Wbf[16 * 72];
  __shared__ float Ws[16][68];
  const int blk = blockIdx.x, bh = blk >> 2, rg = blk & 3;
  const int tid = threadIdx.x, lane = tid & 63, wv = tid >> 6;
  const int r0 = rg * 16;
  const int prow = tid >> 2, pc0 = (tid & 3) * 16;     // MT staging (64 rows)
  const int nrow = tid >> 4, nc0 = (tid & 15) * 4;     // N16 / Wsnap mapping

  for (int i = tid; i < 16 * 72; i += 256) Wbf[i] = 0;
  for (int i = tid; i < 16 * 68; i += 256) (&Ws[0][0])[i] = 0.f;
  __syncthreads();

  size_t base = (size_t)bh * NCH_ * 4096;
  uint4 rm0 = *(const uint4*)&MTg[base + prow * 64 + pc0];
  uint4 rm1 = *(const uint4*)&MTg[base + prow * 64 + pc0 + 8];
  uint2 rn  = *(const uint2*)&Ng[base + (size_t)(r0 + nrow) * 64 + nc0];

  for (int j = 0; j < NCH_; ++j) {
    *(short8*)&MTb[prow * 72 + pc0]     = __builtin_bit_cast(short8, rm0);
    *(short8*)&MTb[prow * 72 + pc0 + 8] = __builtin_bit_cast(short8, rm1);
    *(uint2*)&Nb[nrow * 72 + nc0] = rn;
    {   // snapshot pre-update W16 (safe: after previous end-of-loop barrier)
      size_t sb = base + (size_t)j * 4096;
      uint2 w2v = *(const uint2*)&Wbf[nrow * 72 + nc0];
      *(uint2*)&Wsnap[sb + (size_t)(r0 + nrow) * 64 + nc0] = w2v;
    }
    if (j + 1 < NCH_) {
      size_t nb2 = base + (size_t)(j + 1) * 4096;
      rm0 = *(const uint4*)&MTg[nb2 + prow * 64 + pc0];
      rm1 = *(const uint4*)&MTg[nb2 + prow * 64 + pc0 + 8];
      rn  = *(const uint2*)&Ng[nb2 + (size_t)(r0 + nrow) * 64 + nc0];
    }
    __syncthreads();
    // wave wv: (W16·M) rows 0-15, cols wv*16..+15 (2 MFMA, K=64)
    f32x4 acc = {};
    {
      short8 f0 = *(const short8*)&Wbf[(lane & 15) * 72 + (lane >> 4) * 8];
      short8 f1 = *(const short8*)&Wbf[(lane & 15) * 72 + 32 + (lane >> 4) * 8];
      short8 g0 = *(const short8*)&MTb[(wv * 16 + (lane & 15)) * 72 + (lane >> 4) * 8];
      short8 g1 = *(const short8*)&MTb[(wv * 16 + (lane & 15)) * 72 + 32 + (lane >> 4) * 8];
      acc = __builtin_amdgcn_mfma_f32_16x16x32_bf16(f0, g0, acc, 0, 0, 0);
      acc = __builtin_amdgcn_mfma_f32_16x16x32_bf16(f1, g1, acc, 0, 0, 0);
    }
    #pragma unroll
    for (int jj = 0; jj < 4; ++jj) {
      int row = (lane >> 4) * 4 + jj, col = wv * 16 + (lane & 15);
      float w = Ws[row][col] + bf2f(Nb[row * 72 + col]) - acc[jj];
      Ws[row][col] = w;
      Wbf[row * 72 + col] = f2bf(w);
    }
    __syncthreads();
  }
}

// ---------------------------------------------------------------------------
// Delta p3: Gb/UTb alias Qb/Kb (dead after the three prods) -> LDS 46KB,
// 3 blocks/CU.
// ---------------------------------------------------------------------------
__global__ __launch_bounds__(256, 3) void delta_p3(const u16* __restrict__ qf,
                                                   const u16* __restrict__ Wsnap,
                                                   const u16* __restrict__ CKg,
                                                   const u16* __restrict__ U0Tg,
                                                   u16* __restrict__ attnb)
{
  __shared__ __align__(16) u16 Qb[64 * 72];
  __shared__ __align__(16) u16 Kb[64 * 72];
  __shared__ __align__(16) u16 W0b[64 * 72];
  __shared__ __align__(16) u16 CKb[64 * 72];
  __shared__ __align__(16) u16 U0Tb[64 * 72];
  u16* Gb  = Qb;    // aliases: Qb/Kb dead after the three prods
  u16* UTb = Kb;

  const int id5 = blockIdx.x, bh = id5 >> 5;
  const int b = bh & 7, h = bh >> 3, t0 = (id5 & 31) * 64;
  const int tid = threadIdx.x, lane = tid & 63, wv = tid >> 6, wrow0 = wv * 16;
  const int prow = tid >> 2, pc0 = (tid & 3) * 16;
  const size_t mb = (size_t)id5 * 4096;

  #pragma unroll
  for (int p = 0; p < 2; ++p) {
    int linear = p * 256 + tid, row = linear >> 3, seg = linear & 7;
    size_t gb = ((size_t)(t0 + row) * B_ + b) * QN_;
    uint4 q4 = *(const uint4*)&qf[gb + h * 64 + seg * 8];
    uint4 k4 = *(const uint4*)&qf[gb + 512 + h * 64 + seg * 8];
    uint4 w4 = *(const uint4*)&Wsnap[mb + (size_t)row * 64 + seg * 8];
    *(short8*)&Qb[row * 72 + seg * 8]  = __builtin_bit_cast(short8, q4);
    *(short8*)&Kb[row * 72 + seg * 8]  = __builtin_bit_cast(short8, k4);
    *(short8*)&W0b[row * 72 + seg * 8] = __builtin_bit_cast(short8, w4);
  }
  {
    uint4 c0v = *(const uint4*)&CKg[mb + prow * 64 + pc0];
    uint4 c1v = *(const uint4*)&CKg[mb + prow * 64 + pc0 + 8];
    uint4 u0v = *(const uint4*)&U0Tg[mb + prow * 64 + pc0];
    uint4 u1v = *(const uint4*)&U0Tg[mb + prow * 64 + pc0 + 8];
    *(short8*)&CKb[prow * 72 + pc0]      = __builtin_bit_cast(short8, c0v);
    *(short8*)&CKb[prow * 72 + pc0 + 8]  = __builtin_bit_cast(short8, c1v);
    *(short8*)&U0Tb[prow * 72 + pc0]     = __builtin_bit_cast(short8, u0v);
    *(short8*)&U0Tb[prow * 72 + pc0 + 8] = __builtin_bit_cast(short8, u1v);
  }
  __syncthreads();

  f32x4 ag[4] = {}, ac[4] = {}, ab[4] = {};
  prod64<72, 72>(Qb, Kb, wrow0, lane, ag);    // QK^T
  prod64<72, 72>(W0b, CKb, wrow0, lane, ac);  // (W0·CK^T)[d][t]
  prod64<72, 72>(Qb, W0b, wrow0, lane, ab);   // Q·W0^T
  __syncthreads();                            // Qb/Kb reads complete before overwrite

  #pragma unroll
  for (int c0 = 0; c0 < 4; ++c0)
    #pragma unroll
    for (int j = 0; j < 4; ++j) {
      int row = wrow0 + (lane >> 4) * 4 + j, col = c0 * 16 + (lane & 15);
      Gb[row * 72 + col]  = f2bf(col <= row ? ag[c0][j] : 0.f);
      UTb[row * 72 + col] = f2bf(bf2f(U0Tb[row * 72 + col]) - ac[c0][j]);
    }
  __syncthreads();

  prod64<72, 72>(Gb, UTb, wrow0, lane, ab);   // += G·U

  #pragma unroll
  for (int c0 = 0; c0 < 4; ++c0)
    #pragma unroll
    for (int j = 0; j < 4; ++j) {
      int row = wrow0 + (lane >> 4) * 4 + j, col = c0 * 16 + (lane & 15);
      attnb[((size_t)(t0 + row) * B_ + b) * HID_ + h * 64 + col] = f2bf(ab[c0][j]);
    }
}

// ---------------------------------------------------------------------------
extern "C" void kernel_launch(void* const* d_in, const int* in_sizes, int n_in,
                              void* d_out, int out_size, void* d_ws, size_t ws_size,
                              hipStream_t stream)
{
  const float* x        = (const float*)d_in[0];
  const float* ip_w     = (const float*)d_in[1];
  const float* ip_b     = (const float*)d_in[2];
  const float* fw_ln_g  = (const float*)d_in[3];
  const float* fw_ln_b  = (const float*)d_in[4];
  const float* fw_slow_w = (const float*)d_in[5];
  const float* fw_out_w  = (const float*)d_in[6];
  const float* ff_ln_g  = (const float*)d_in[7];
  const float* ff_ln_b  = (const float*)d_in[8];
  const float* ff_w1    = (const float*)d_in[9];
  const float* ff_b1    = (const float*)d_in[10];
  const float* ff_w2    = (const float*)d_in[11];
  const float* ff_b2    = (const float*)d_in[12];
  float* out = (float*)d_out;

  const int M = B_ * S_;  // 16384
  const size_t matN = (size_t)64 * NCH_ * 4096;   // 8.39M elems

  const size_t nIp = 512 * 512, nOut = 512 * 512;
  const size_t nSlow = (size_t)QN_ * 512;
  const size_t nW1 = (size_t)FF_ * 512, nW2 = (size_t)512 * FF_;
  const size_t nXbf = (size_t)M * HID_;
  const size_t poolElems = nIp + 2 * nSlow + 2 * nOut + nW1 + nW2 + nXbf + matN;

  size_t need = (size_t)M * HID_ * 4
              + ((size_t)M * QN_ + 2 * matN + poolElems) * 2;
  if (ws_size < need) return;

  float* cur   = (float*)d_ws;
  u16*   qkvbf = (u16*)(cur + (size_t)M * HID_);            // [M][1664] bf16
  u16*   attnSlot = qkvbf + (size_t)M * QN_;                // 2*matN u16
  u16*   MTg   = attnSlot;
  u16*   Ng    = MTg + matN;
  u16*   attnb = attnSlot;                                  // reuses MTg after p2
  u16*   CKg   = (u16*)out;
  u16*   U0Tg  = CKg + matN;
  u16*   tmpbf = (u16*)out;                                 // LN out; dead when CKg live
  u16*   hiddenb = qkvbf;                                   // FFN hidden

  u16* pool = attnSlot + 2 * matN;
  u16* ipwb   = pool;               pool += nIp;
  u16* slowb0 = pool;               pool += nSlow;
  u16* slowb1 = pool;               pool += nSlow;
  u16* outwb0 = pool;               pool += nOut;
  u16* outwb1 = pool;               pool += nOut;
  u16* w1b    = pool;               pool += nW1;
  u16* w2b    = pool;               pool += nW2;
  u16* Wsnap  = pool;               pool += matN;
  u16* xbf    = pool;

  dim3 blk(256);

  conv_all<<<14592, blk, 0, stream>>>(ip_w, fw_slow_w, fw_out_w, ff_w1, ff_w2,
                                      ipwb, slowb0, slowb1, outwb0, outwb1, w1b, w2b);
  conv_x<<<M, 64, 0, stream>>>(x, xbf);

  gemm_bf<true, false, false, false, false, false><<<4 * 128, blk, 0, stream>>>(
      xbf, ipwb, ip_b, nullptr, cur, M, HID_, HID_, 4);

  for (int layer = 0; layer < 2; ++layer) {
    u16* slowb = layer ? slowb1 : slowb0;
    u16* outwb = layer ? outwb1 : outwb0;

    ln_bf<<<M, 64, 0, stream>>>(cur, fw_ln_g + layer * HID_, fw_ln_b + layer * HID_, tmpbf);
    gemm_bf<false, false, false, true, false, true><<<13 * 128, blk, 0, stream>>>(
        tmpbf, slowb, nullptr, nullptr, qkvbf, M, QN_, HID_, 13);
    delta_p1<<<64 * NCH_, 256, 0, stream>>>(qkvbf, MTg, Ng, CKg, U0Tg);
    delta_p2<<<256, 256, 0, stream>>>(MTg, Ng, Wsnap);
    delta_p3<<<64 * NCH_, 256, 0, stream>>>(qkvbf, Wsnap, CKg, U0Tg, attnb);
    if (layer == 0) {
      gemm_bf<false, false, true, false, false, false><<<4 * 128, blk, 0, stream>>>(
          attnb, outwb, nullptr, cur, cur, M, HID_, HID_, 4);
      ln_bf<<<M, 64, 0, stream>>>(cur, ff_ln_g, ff_ln_b, tmpbf);
      gemm_bf<true, true, false, true, false, false><<<16 * 128, blk, 0, stream>>>(
          tmpbf, w1b, ff_b1, nullptr, hiddenb, M, FF_, HID_, 16);
      gemm_bf<true, false, true, false, false, false><<<4 * 128, blk, 0, stream>>>(
          hiddenb, w2b, ff_b2, cur, cur, M, HID_, FF_, 4);
    } else {
      // final out-proj writes [B,S,512] directly (fused transpose)
      gemm_bf<false, false, true, false, true, false><<<4 * 128, blk, 0, stream>>>(
          attnb, outwb, nullptr, cur, out, M, HID_, HID_, 4);
    }
  }
}